// Round 3
// baseline (807.244 us; speedup 1.0000x reference)
//
#include <hip/hip_runtime.h>

// MDDNet GNN layer — round 3: dst-sorted edges + run-combined atomics.
// N=20000, E=320000, D=128, H1=256, H2=512, H3=1024, K3=640.

constexpr int D  = 128;
constexpr int H1 = 256;
constexpr int H2 = 512;
constexpr int H3 = 1024;
constexpr int K3 = D + H2;   // 640

typedef short  bf16x8 __attribute__((ext_vector_type(8)));
typedef ushort u16x8  __attribute__((ext_vector_type(8)));
typedef float  f32x4  __attribute__((ext_vector_type(4)));

__device__ __forceinline__ float leaky(float x) { return x >= 0.f ? x : 0.01f * x; }

// f32 -> bf16 round-to-nearest-even
__device__ __forceinline__ ushort f2bf(float f) {
    unsigned u = __float_as_uint(f);
    u += 0x7FFFu + ((u >> 16) & 1u);
    return (ushort)(u >> 16);
}

// LDS XOR swizzle (T2/G4)
__device__ __forceinline__ int swz(int row, int bytecol) {
    return bytecol ^ ((row & 7) << 4);
}

__device__ __forceinline__ f32x4 mfma16(bf16x8 a, bf16x8 b, f32x4 c) {
    return __builtin_amdgcn_mfma_f32_16x16x32_bf16(a, b, c, 0, 0, 0);
}

// ---------------------------------------------------------------------------
// Counting sort of edges by dst: hist -> single-wave scan -> scatter.
// Order within a node is nondeterministic (atomic bump) -> only reorders the
// fp32 accumulation, jitter ~1e-6 vs threshold 5.4e-2.
// ---------------------------------------------------------------------------
__global__ __launch_bounds__(256) void hist_kernel(
    const int* __restrict__ dst, int* __restrict__ cursor, int E)
{
    const int i = blockIdx.x * 256 + threadIdx.x;
    if (i < E) atomicAdd(&cursor[dst[i]], 1);
}

__global__ __launch_bounds__(64) void scan_kernel(int* __restrict__ cursor, int n)
{
    const int lane = threadIdx.x;
    int base = 0;
    for (int c0 = 0; c0 < n; c0 += 64) {
        const int i = c0 + lane;
        const int v = (i < n) ? cursor[i] : 0;
        int incl = v;
        #pragma unroll
        for (int d = 1; d < 64; d <<= 1) {
            const int t = __shfl_up(incl, d);
            if (lane >= d) incl += t;
        }
        if (i < n) cursor[i] = base + incl - v;   // exclusive prefix
        base += __shfl(incl, 63);
    }
}

__global__ __launch_bounds__(256) void scatter_kernel(
    const int* __restrict__ dst, int* __restrict__ cursor,
    int* __restrict__ perm, int E)
{
    const int i = blockIdx.x * 256 + threadIdx.x;
    if (i < E) {
        const int pos = atomicAdd(&cursor[dst[i]], 1);
        perm[pos] = i;
    }
}

// ---------------------------------------------------------------------------
// Pack fp32 W[K][Nc] into bf16 B-fragment tile order for mfma_16x16x32_bf16.
// ---------------------------------------------------------------------------
__global__ __launch_bounds__(256) void pack_weights(
    const float* __restrict__ W, ushort* __restrict__ Wp, int K, int Nc)
{
    const int KT    = K >> 5;
    const int total = (Nc >> 4) * KT * 64;
    const int idx   = blockIdx.x * 256 + threadIdx.x;
    if (idx >= total) return;
    const int l   = idx & 63;
    const int tt  = idx >> 6;
    const int ks  = tt % KT;
    const int ni  = tt / KT;
    const int col = ni * 16 + (l & 15);
    const int k0  = ks * 32 + (l >> 4) * 8;
    u16x8 u;
    #pragma unroll
    for (int j = 0; j < 8; ++j) u[j] = f2bf(W[(size_t)(k0 + j) * Nc + col]);
    *(u16x8*)(Wp + (size_t)idx * 8) = u;
}

// ---------------------------------------------------------------------------
// Edge pipeline fused, edges pre-sorted by dst via perm[].
// t = bf16(x0[src]*ea); m1 = leaky(t@W1+b1); m2 = leaky(m1@W2+b2);
// run-combined atomicAdd into aggr[dst].
// ---------------------------------------------------------------------------
constexpr int TE = 64;

__global__ __launch_bounds__(256) void edge_mlp_mfma(
    const float* __restrict__ x0, const int* __restrict__ src,
    const int* __restrict__ dst, const float* __restrict__ ea,
    const int* __restrict__ perm,
    const ushort* __restrict__ W1p, const float* __restrict__ b1,
    const ushort* __restrict__ W2p, const float* __restrict__ b2,
    float* __restrict__ aggr)
{
    __shared__ __align__(16) ushort t_lds[TE * D];     // 16 KB
    __shared__ __align__(16) ushort m1_lds[TE * H1];   // 32 KB
    __shared__ int sidx[TE], didx[TE], pidx[TE];

    const int tid  = threadIdx.x;
    const int e0   = blockIdx.x * TE;
    const int lane = tid & 63;
    const int w    = tid >> 6;
    const int lr   = lane & 15;
    const int lg   = lane >> 4;

    if (tid < TE) {
        const int p = perm[e0 + tid];
        pidx[tid] = p;
        sidx[tid] = src[p];
        didx[tid] = dst[p];
    }
    __syncthreads();

    // stage t: 64 rows x 16 chunks of 16B (8 bf16), 4 chunks/thread
    #pragma unroll
    for (int i = 0; i < 4; ++i) {
        const int c    = i * 256 + tid;
        const int row  = c >> 4;
        const int slot = c & 15;
        const float4* xp = (const float4*)(x0 + (size_t)sidx[row] * D + slot * 8);
        const float4* ep = (const float4*)(ea + (size_t)pidx[row] * D + slot * 8);
        const float4 xa = xp[0], xb = xp[1];
        const float4 ga = ep[0], gb = ep[1];
        u16x8 u;
        u[0] = f2bf(xa.x * ga.x); u[1] = f2bf(xa.y * ga.y);
        u[2] = f2bf(xa.z * ga.z); u[3] = f2bf(xa.w * ga.w);
        u[4] = f2bf(xb.x * gb.x); u[5] = f2bf(xb.y * gb.y);
        u[6] = f2bf(xb.z * gb.z); u[7] = f2bf(xb.w * gb.w);
        *(u16x8*)((char*)t_lds + row * 256 + swz(row, slot * 16)) = u;
    }
    __syncthreads();

    // GEMM1: m1[64][256] = leaky(t @ W1 + b1)
    {
        f32x4 acc[4][4];
        #pragma unroll
        for (int ntl = 0; ntl < 4; ++ntl) {
            const float b = b1[(w * 4 + ntl) * 16 + lr];
            #pragma unroll
            for (int mt = 0; mt < 4; ++mt) acc[mt][ntl] = (f32x4){b, b, b, b};
        }
        #pragma unroll
        for (int ks = 0; ks < 4; ++ks) {
            bf16x8 af[4];
            #pragma unroll
            for (int mt = 0; mt < 4; ++mt) {
                const int row = mt * 16 + lr;
                af[mt] = *(const bf16x8*)((const char*)t_lds + row * 256 +
                                          swz(row, ks * 64 + lg * 16));
            }
            #pragma unroll
            for (int ntl = 0; ntl < 4; ++ntl) {
                const bf16x8 bf = *(const bf16x8*)(W1p +
                    ((size_t)((w * 4 + ntl) * 4 + ks) * 64 + lane) * 8);
                #pragma unroll
                for (int mt = 0; mt < 4; ++mt)
                    acc[mt][ntl] = mfma16(af[mt], bf, acc[mt][ntl]);
            }
        }
        #pragma unroll
        for (int mt = 0; mt < 4; ++mt)
            #pragma unroll
            for (int ntl = 0; ntl < 4; ++ntl)
                #pragma unroll
                for (int r = 0; r < 4; ++r) {
                    const int row = mt * 16 + lg * 4 + r;
                    const int col = (w * 4 + ntl) * 16 + lr;
                    *(ushort*)((char*)m1_lds + row * 512 + swz(row, col * 2)) =
                        f2bf(leaky(acc[mt][ntl][r]));
                }
    }
    __syncthreads();

    // GEMM2: m2[64][512] = leaky(m1 @ W2 + b2) -> run-combined atomic scatter.
    int dnode[4][4];
    #pragma unroll
    for (int mt = 0; mt < 4; ++mt)
        #pragma unroll
        for (int r = 0; r < 4; ++r)
            dnode[mt][r] = didx[mt * 16 + lg * 4 + r];

    #pragma unroll
    for (int g = 0; g < 2; ++g) {
        f32x4 acc[4][4];
        #pragma unroll
        for (int ntl = 0; ntl < 4; ++ntl) {
            const float b = b2[(w * 8 + g * 4 + ntl) * 16 + lr];
            #pragma unroll
            for (int mt = 0; mt < 4; ++mt) acc[mt][ntl] = (f32x4){b, b, b, b};
        }
        #pragma unroll
        for (int ks = 0; ks < 8; ++ks) {
            bf16x8 af[4];
            #pragma unroll
            for (int mt = 0; mt < 4; ++mt) {
                const int row = mt * 16 + lr;
                af[mt] = *(const bf16x8*)((const char*)m1_lds + row * 512 +
                                          swz(row, ks * 64 + lg * 16));
            }
            #pragma unroll
            for (int ntl = 0; ntl < 4; ++ntl) {
                const bf16x8 bf = *(const bf16x8*)(W2p +
                    ((size_t)((w * 8 + g * 4 + ntl) * 8 + ks) * 64 + lane) * 8);
                #pragma unroll
                for (int mt = 0; mt < 4; ++mt)
                    acc[mt][ntl] = mfma16(af[mt], bf, acc[mt][ntl]);
            }
        }
        // per-lane run combining: 4 consecutive sorted rows usually share dst
        #pragma unroll
        for (int mt = 0; mt < 4; ++mt)
            #pragma unroll
            for (int ntl = 0; ntl < 4; ++ntl) {
                const int col = (w * 8 + g * 4 + ntl) * 16 + lr;
                float s = leaky(acc[mt][ntl][0]);
                #pragma unroll
                for (int r = 1; r < 4; ++r) {
                    const float v = leaky(acc[mt][ntl][r]);
                    if (dnode[mt][r] == dnode[mt][r - 1]) {
                        s += v;
                    } else {
                        atomicAdd(&aggr[(size_t)dnode[mt][r - 1] * H2 + col], s);
                        s = v;
                    }
                }
                atomicAdd(&aggr[(size_t)dnode[mt][3] * H2 + col], s);
            }
    }
}

// ---------------------------------------------------------------------------
// h[N][1024] = bf16(leaky(concat(x0, aggr) @ W3 + b3))
// ---------------------------------------------------------------------------
constexpr int TN = 32;

__global__ __launch_bounds__(256) void node_mlp1_mfma(
    const float* __restrict__ x0, const float* __restrict__ aggr,
    const ushort* __restrict__ W3p, const float* __restrict__ b3,
    ushort* __restrict__ h)
{
    __shared__ __align__(16) ushort a_lds[TN * K3];  // 40 KB
    const int tid  = threadIdx.x;
    const int n0   = blockIdx.x * TN;
    const int ch   = blockIdx.y;
    const int lane = tid & 63;
    const int w    = tid >> 6;
    const int lr   = lane & 15;
    const int lg   = lane >> 4;

    #pragma unroll
    for (int i = 0; i < 10; ++i) {
        const int c    = i * 256 + tid;
        const int row  = c / 80;
        const int slot = c % 80;
        const float* sp = (slot < 16)
            ? x0   + (size_t)(n0 + row) * D  + slot * 8
            : aggr + (size_t)(n0 + row) * H2 + (slot - 16) * 8;
        const float4 va = ((const float4*)sp)[0];
        const float4 vb = ((const float4*)sp)[1];
        u16x8 u;
        u[0] = f2bf(va.x); u[1] = f2bf(va.y); u[2] = f2bf(va.z); u[3] = f2bf(va.w);
        u[4] = f2bf(vb.x); u[5] = f2bf(vb.y); u[6] = f2bf(vb.z); u[7] = f2bf(vb.w);
        *(u16x8*)((char*)a_lds + row * 1280 + swz(row, slot * 16)) = u;
    }
    __syncthreads();

    #pragma unroll
    for (int g = 0; g < 2; ++g) {
        f32x4 acc[2][4];
        #pragma unroll
        for (int ntl = 0; ntl < 4; ++ntl) {
            const int colg = ch * 512 + (w * 8 + g * 4 + ntl) * 16 + lr;
            const float b = b3[colg];
            #pragma unroll
            for (int mt = 0; mt < 2; ++mt) acc[mt][ntl] = (f32x4){b, b, b, b};
        }
        for (int ks = 0; ks < 20; ++ks) {
            bf16x8 af[2];
            #pragma unroll
            for (int mt = 0; mt < 2; ++mt) {
                const int row = mt * 16 + lr;
                af[mt] = *(const bf16x8*)((const char*)a_lds + row * 1280 +
                                          swz(row, ks * 64 + lg * 16));
            }
            #pragma unroll
            for (int ntl = 0; ntl < 4; ++ntl) {
                const int nt = ch * 32 + w * 8 + g * 4 + ntl;
                const bf16x8 bf = *(const bf16x8*)(W3p +
                    ((size_t)(nt * 20 + ks) * 64 + lane) * 8);
                #pragma unroll
                for (int mt = 0; mt < 2; ++mt)
                    acc[mt][ntl] = mfma16(af[mt], bf, acc[mt][ntl]);
            }
        }
        #pragma unroll
        for (int mt = 0; mt < 2; ++mt)
            #pragma unroll
            for (int ntl = 0; ntl < 4; ++ntl) {
                const int colg = ch * 512 + (w * 8 + g * 4 + ntl) * 16 + lr;
                #pragma unroll
                for (int r = 0; r < 4; ++r) {
                    const int row = n0 + mt * 16 + lg * 4 + r;
                    h[(size_t)row * H3 + colg] = f2bf(leaky(acc[mt][ntl][r]));
                }
            }
    }
}

// ---------------------------------------------------------------------------
// out = ((h @ W4 + b4)·BN + x0) / 2
// ---------------------------------------------------------------------------
__global__ __launch_bounds__(256) void node_mlp2_mfma(
    const ushort* __restrict__ h, const float* __restrict__ x0,
    const ushort* __restrict__ W4p, const float* __restrict__ b4,
    const float* __restrict__ gamma, const float* __restrict__ beta,
    const float* __restrict__ mean, const float* __restrict__ var,
    float* __restrict__ out)
{
    const int tid  = threadIdx.x;
    const int n0   = blockIdx.x * TN;
    const int lane = tid & 63;
    const int w    = tid >> 6;
    const int lr   = lane & 15;
    const int lg   = lane >> 4;

    f32x4 acc[2][2];
    #pragma unroll
    for (int ntl = 0; ntl < 2; ++ntl) {
        const float b = b4[(w * 2 + ntl) * 16 + lr];
        #pragma unroll
        for (int mt = 0; mt < 2; ++mt) acc[mt][ntl] = (f32x4){b, b, b, b};
    }
    for (int ks = 0; ks < 32; ++ks) {
        bf16x8 af[2];
        #pragma unroll
        for (int mt = 0; mt < 2; ++mt)
            af[mt] = *(const bf16x8*)(h + (size_t)(n0 + mt * 16 + lr) * H3 +
                                      ks * 32 + lg * 8);
        #pragma unroll
        for (int ntl = 0; ntl < 2; ++ntl) {
            const bf16x8 bf = *(const bf16x8*)(W4p +
                ((size_t)((w * 2 + ntl) * 32 + ks) * 64 + lane) * 8);
            #pragma unroll
            for (int mt = 0; mt < 2; ++mt)
                acc[mt][ntl] = mfma16(af[mt], bf, acc[mt][ntl]);
        }
    }
    #pragma unroll
    for (int ntl = 0; ntl < 2; ++ntl) {
        const int col = (w * 2 + ntl) * 16 + lr;
        const float sc = gamma[col] * rsqrtf(var[col] + 1e-5f);
        const float bo = beta[col] - mean[col] * sc;
        #pragma unroll
        for (int mt = 0; mt < 2; ++mt)
            #pragma unroll
            for (int r = 0; r < 4; ++r) {
                const int row = n0 + mt * 16 + lg * 4 + r;
                const float v = acc[mt][ntl][r] * sc + bo;
                out[(size_t)row * D + col] =
                    0.5f * (v + x0[(size_t)row * D + col]);
            }
    }
}

extern "C" void kernel_launch(void* const* d_in, const int* in_sizes, int n_in,
                              void* d_out, int out_size, void* d_ws, size_t ws_size,
                              hipStream_t stream)
{
    const float* x0    = (const float*)d_in[0];
    const int*   ei    = (const int*)d_in[1];
    const float* ea    = (const float*)d_in[2];
    const float* W1    = (const float*)d_in[3];
    const float* b1    = (const float*)d_in[4];
    const float* W2    = (const float*)d_in[5];
    const float* b2    = (const float*)d_in[6];
    const float* W3    = (const float*)d_in[7];
    const float* b3    = (const float*)d_in[8];
    const float* W4    = (const float*)d_in[9];
    const float* b4    = (const float*)d_in[10];
    const float* gamma = (const float*)d_in[11];
    const float* beta  = (const float*)d_in[12];
    const float* mean  = (const float*)d_in[13];
    const float* var   = (const float*)d_in[14];
    float* out = (float*)d_out;

    const int N = in_sizes[0] / D;   // 20000
    const int E = in_sizes[2] / D;   // 320000
    const int* src = ei;
    const int* dst = ei + E;

    char* ws = (char*)d_ws;
    float*  aggr = (float*)ws;                                   // N*H2 f32
    ushort* h    = (ushort*)(ws + (size_t)N * H2 * 4);           // N*H3 bf16
    // sort scratch aliases h: h is only written by node_mlp1, AFTER the edge
    // kernel has fully consumed cursor/perm.
    int* cursor = (int*)h;           // N ints
    int* perm   = (int*)h + N;       // E ints
    ushort* W1p  = (ushort*)(ws + (size_t)N * H2 * 4 + (size_t)N * H3 * 2);
    ushort* W2p  = W1p + (size_t)(D  / 32) * (H1 / 16) * 512;
    ushort* W3p  = W2p + (size_t)(H1 / 32) * (H2 / 16) * 512;
    ushort* W4p  = W3p + (size_t)(K3 / 32) * (H3 / 16) * 512;

    hipMemsetAsync(aggr, 0, (size_t)N * H2 * sizeof(float), stream);
    hipMemsetAsync(cursor, 0, (size_t)N * sizeof(int), stream);

    pack_weights<<<(4096  + 255) / 256, 256, 0, stream>>>(W1, W1p, D,  H1);
    pack_weights<<<(16384 + 255) / 256, 256, 0, stream>>>(W2, W2p, H1, H2);
    pack_weights<<<(81920 + 255) / 256, 256, 0, stream>>>(W3, W3p, K3, H3);
    pack_weights<<<(16384 + 255) / 256, 256, 0, stream>>>(W4, W4p, H3, D);

    // counting sort by dst
    hist_kernel<<<(E + 255) / 256, 256, 0, stream>>>(dst, cursor, E);
    scan_kernel<<<1, 64, 0, stream>>>(cursor, N);
    scatter_kernel<<<(E + 255) / 256, 256, 0, stream>>>(dst, cursor, perm, E);

    edge_mlp_mfma<<<E / TE, 256, 0, stream>>>(x0, src, dst, ea, perm,
                                              W1p, b1, W2p, b2, aggr);
    dim3 g1(N / TN, 2);
    node_mlp1_mfma<<<g1, 256, 0, stream>>>(x0, aggr, W3p, b3, h);
    node_mlp2_mfma<<<N / TN, 256, 0, stream>>>(h, x0, W4p, b4, gamma, beta, mean, var, out);
}